// Round 6
// baseline (1901.360 us; speedup 1.0000x reference)
//
#include <hip/hip_runtime.h>
#include <hip/hip_bf16.h>
#include <stdint.h>

#define N_RES 4096
#define BATCH 8
#define T_STEPS 256
#define VOCAB 32000
#define R_OUT 512
#define NNZ 131072
#define NNZ_CAP 163840
#define TEAMS 8             // one per batch
#define SLICES 16           // WGs per team
#define ROWS_PS 256         // rows per WG
#define NWG (TEAMS*SLICES)  // 128
#define CSR_CAP 10240       // entries per slice in LDS (mean ~9088, +11 sigma)

typedef _Float16 v8h __attribute__((ext_vector_type(8)));
typedef float v4f __attribute__((ext_vector_type(4)));

static __device__ __forceinline__ unsigned short f2h(float f) {
    _Float16 h = (_Float16)f;
    unsigned short u;
    __builtin_memcpy(&u, &h, 2);
    return u;
}
static __device__ __forceinline__ float h2f(unsigned short u) {
    _Float16 h;
    __builtin_memcpy(&h, &u, 2);
    return (float)h;
}

// ---------------- init / CSR build ----------------

__global__ __launch_bounds__(256) void k_hist(const int* __restrict__ rows,
                                              int* __restrict__ cnt) {
    int i = blockIdx.x * 256 + threadIdx.x;
    if (i < NNZ) atomicAdd(&cnt[rows[i]], 1);
}

// padded scan: each row's span rounded up to multiple of 8
__global__ __launch_bounds__(1024) void k_scan(const int* __restrict__ cnt,
                                               int* __restrict__ row_ptr,
                                               int* __restrict__ cursor) {
    __shared__ int sm[1024];
    int t = threadIdx.x;
    int base = t * 4;
    int c0 = (cnt[base] + 7) & ~7;
    int c1 = (cnt[base + 1] + 7) & ~7;
    int c2 = (cnt[base + 2] + 7) & ~7;
    int c3 = (cnt[base + 3] + 7) & ~7;
    int s = c0 + c1 + c2 + c3;
    sm[t] = s;
    __syncthreads();
    for (int off = 1; off < 1024; off <<= 1) {
        int v = (t >= off) ? sm[t - off] : 0;
        __syncthreads();
        sm[t] += v;
        __syncthreads();
    }
    int run = sm[t] - s;
    row_ptr[base] = run;     cursor[base] = run;     run += c0;
    row_ptr[base + 1] = run; cursor[base + 1] = run; run += c1;
    row_ptr[base + 2] = run; cursor[base + 2] = run; run += c2;
    row_ptr[base + 3] = run; cursor[base + 3] = run; run += c3;
    if (t == 1023) row_ptr[4096] = run;
}

// packed CSR entry: plane BYTE offset (col*4) in hi16, f16 value in lo16.
__global__ __launch_bounds__(256) void k_fill(const int* __restrict__ rows,
                                              const int* __restrict__ cols,
                                              const float* __restrict__ vals,
                                              int* __restrict__ cursor,
                                              unsigned* __restrict__ csr) {
    int i = blockIdx.x * 256 + threadIdx.x;
    if (i < NNZ) {
        int r = rows[i];
        unsigned off = (unsigned)(cols[i] << 2);
        int p = atomicAdd(&cursor[r], 1);
        csr[p] = (off << 16) | (unsigned)f2h(vals[i]);
    }
}

// ---------------- f32 -> f16 convert (for B_w, A_w) ----------------

__global__ __launch_bounds__(256) void k_cvt(const float* __restrict__ src,
                                             unsigned short* __restrict__ dst, int n) {
    int i = (blockIdx.x * 256 + threadIdx.x) * 8;
    if (i < n) {
        float4 a0 = *reinterpret_cast<const float4*>(src + i);
        float4 a1 = *reinterpret_cast<const float4*>(src + i + 4);
        unsigned short o[8] = { f2h(a0.x), f2h(a0.y), f2h(a0.z), f2h(a0.w),
                                f2h(a1.x), f2h(a1.y), f2h(a1.z), f2h(a1.w) };
        *reinterpret_cast<uint4*>(dst + i) = *reinterpret_cast<const uint4*>(o);
    }
}

// ---------------- persistent recurrence ----------------
// 128 WGs x 256 threads. team = wg&7 (batch), slice = wg>>3 (256 rows).
// Publish: one 4B relaxed agent store per thread (lane-contiguous ->
// coalesced); vmcnt(0); syncthreads; tid 0 stores the WG epoch flag.
// Gate: wave 0 only, lane l polls flag (l&15) -> ONE load instr samples all
// 16 flags; syncthreads. Pull: 8 coalesced u64 rounds x64[k*256+tid]
// (512B/instr); rows arrive as 2*(k*256+tid), so the IDENTITY plane layout
// is conflict-free for the float2 refill writes (bank = 2*tid&31, 2-way).
// Safety: flag[w] >= e implies WG w finished consuming epoch e-1 (its pull
// feeds the compute of e by data dependency), so parity-buffer words of
// epoch e-1 are never overwritten (at publish e+1) before all readers done.
// Flags memset to 0 every launch -> replay-safe; stale hx unreachable.

__global__ __launch_bounds__(256) void k_steps(const int* __restrict__ rowptr,
                                               const unsigned* __restrict__ csr,
                                               const float* __restrict__ W_in,
                                               const int* __restrict__ x,
                                               const float* __restrict__ a,
                                               unsigned short* __restrict__ Hb,
                                               unsigned* __restrict__ hx,
                                               unsigned* __restrict__ flags) {
    __shared__ float plane[2][4096];                    // 32 KB, identity layout
    __shared__ __align__(16) unsigned lcsr[CSR_CAP];    // 40 KB
    __shared__ int ltok[T_STEPS];                       // 1 KB

    int wg = blockIdx.x;
    int tid = threadIdx.x;
    int team = wg & 7;
    int slice = wg >> 3;
    int r_own = slice * ROWS_PS + tid;

    ltok[tid] = x[team * T_STEPS + tid];

    int j0 = rowptr[slice * ROWS_PS];
    int j1 = rowptr[slice * ROWS_PS + ROWS_PS];
    int cntE = j1 - j0;
    if (cntE > CSR_CAP) cntE = CSR_CAP;
    {
        const uint4* src = reinterpret_cast<const uint4*>(csr + j0);
        int n4 = cntE >> 2;
        for (int k = tid; k < n4; k += 256)
            reinterpret_cast<uint4*>(lcsr)[k] = src[k];
    }
    for (int k = tid; k < 4096; k += 256) plane[0][k] = 0.f;

    int js = rowptr[r_own] - j0;
    int je = rowptr[r_own + 1] - j0;
    if (js > CSR_CAP) js = CSR_CAP;
    if (je > CSR_CAP) je = CSR_CAP;
    float av = a[r_own];
    float oma = 1.f - av;
    __syncthreads();

    float u_cur = W_in[(size_t)ltok[0] * N_RES + r_own];

    for (int t = 0; t < T_STEPS; ++t) {
        const float* pc = plane[t & 1];

        float acc = 0.f;
        for (int j = js; j < je; j += 8) {
            uint4 e0 = *reinterpret_cast<const uint4*>(lcsr + j);
            uint4 e1 = *reinterpret_cast<const uint4*>(lcsr + j + 4);
            unsigned ee[8] = { e0.x, e0.y, e0.z, e0.w, e1.x, e1.y, e1.z, e1.w };
#pragma unroll
            for (int q = 0; q < 8; ++q) {
                float g = *reinterpret_cast<const float*>(
                    reinterpret_cast<const char*>(pc) + (ee[q] >> 16));
                acc += h2f((unsigned short)(ee[q] & 0xffffu)) * g;
            }
        }
        float hold = pc[r_own];
        float pre = u_cur + acc;
        pre = fminf(fmaxf(pre, -10.f), 10.f);
        float ex = __expf(2.f * pre);
        float th = 1.f - 2.f / (ex + 1.f);
        float hv = oma * hold + av * th;
        unsigned short hv16 = f2h(hv);

        if (t == T_STEPS - 1) {
            Hb[((size_t)(team * T_STEPS + t) << 12) + r_own] = hv16;
            break;
        }

        unsigned e = (unsigned)(t + 1);
        unsigned* xbase = hx + (((size_t)(e & 1u) * TEAMS + team) << 12);

        // publish own row: single 4B agent store, lane-contiguous
        __hip_atomic_store(xbase + r_own, (unsigned)hv16,
                           __ATOMIC_RELAXED, __HIP_MEMORY_SCOPE_AGENT);
        asm volatile("s_waitcnt vmcnt(0)" ::: "memory");   // payload ack
        __syncthreads();                                   // all waves acked
        if (tid == 0)
            __hip_atomic_store(flags + (team * SLICES + slice) * 32, e,
                               __ATOMIC_RELAXED, __HIP_MEMORY_SCOPE_AGENT);

        // off-critical-path work in the gate shadow
        float u_nxt = W_in[(size_t)ltok[t + 1] * N_RES + r_own];
        Hb[((size_t)(team * T_STEPS + t) << 12) + r_own] = hv16;

        // gate: wave 0 samples all 16 team flags with one load instr
        if (tid < 64) {
            const unsigned* fp = flags + (team * SLICES + (tid & 15)) * 32;
            while (__hip_atomic_load(fp, __ATOMIC_RELAXED,
                                     __HIP_MEMORY_SCOPE_AGENT) < e) {}
        }
        __syncthreads();

        // pull: 8 coalesced u64 rounds, refill other plane (identity layout)
        const unsigned long long* x64 =
            reinterpret_cast<const unsigned long long*>(xbase);
        float* pn = plane[(t + 1) & 1];
#pragma unroll
        for (int k = 0; k < 8; ++k) {
            unsigned long long d = __hip_atomic_load(x64 + k * 256 + tid,
                                                     __ATOMIC_RELAXED,
                                                     __HIP_MEMORY_SCOPE_AGENT);
            float2 v;
            v.x = h2f((unsigned short)(d & 0xffffu));
            v.y = h2f((unsigned short)((d >> 32) & 0xffffu));
            *reinterpret_cast<float2*>(&pn[(k * 256 + tid) * 2]) = v;
        }
        u_cur = u_nxt;
        __syncthreads();            // new plane ready (old plane untouched)
    }
}

// ---------------- GEMM1: Rbh(2048x512,f16) = Hb(2048x4096,f16) @ Bwh^T ----------------

__global__ __launch_bounds__(512) void k_gemm1(const unsigned short* __restrict__ Hb,
                                               const unsigned short* __restrict__ Bwh,
                                               unsigned short* __restrict__ Rbh) {
    int lane = threadIdx.x & 63, wave = threadIdx.x >> 6;
    int wm = wave >> 1, wn = wave & 1;
    int row0 = blockIdx.y * 128;
    int col0 = blockIdx.x * 128 + wn * 64;
    int rA = lane & 15, kA = (lane >> 4) * 8;
    v4f acc[2][4];
    for (int s = 0; s < 2; ++s)
        for (int f = 0; f < 4; ++f)
            acc[s][f] = (v4f){0.f, 0.f, 0.f, 0.f};

    for (int k0 = 0; k0 < N_RES; k0 += 32) {
        v8h af[2];
#pragma unroll
        for (int s = 0; s < 2; ++s) {
            int r = row0 + (wm * 2 + s) * 16 + rA;
            af[s] = *reinterpret_cast<const v8h*>(Hb + (size_t)r * N_RES + k0 + kA);
        }
        v8h bf[4];
#pragma unroll
        for (int f = 0; f < 4; ++f) {
            int c = col0 + f * 16 + rA;
            bf[f] = *reinterpret_cast<const v8h*>(Bwh + (size_t)c * N_RES + k0 + kA);
        }
#pragma unroll
        for (int s = 0; s < 2; ++s)
#pragma unroll
            for (int f = 0; f < 4; ++f)
                acc[s][f] = __builtin_amdgcn_mfma_f32_16x16x32_f16(af[s], bf[f], acc[s][f], 0, 0, 0);
    }
#pragma unroll
    for (int s = 0; s < 2; ++s)
#pragma unroll
        for (int f = 0; f < 4; ++f) {
            int col = col0 + f * 16 + (lane & 15);
#pragma unroll
            for (int r = 0; r < 4; ++r) {
                int row = row0 + (wm * 2 + s) * 16 + (lane >> 4) * 4 + r;
                Rbh[(size_t)row * R_OUT + col] = f2h(acc[s][f][r]);
            }
        }
}

// ---------------- GEMM2: out(2048x32000,f32) = Rbh(f16) @ Awh^T + Ab ----------------
// grid.x = col-blocks (250) fastest -> each XCD sees cols {bx mod 8}: its Awh
// working set is ~4MB, L2-resident across all row-blocks (no 8x re-fetch).

__global__ __launch_bounds__(512) void k_gemm2(const unsigned short* __restrict__ Rbh,
                                               const unsigned short* __restrict__ Awh,
                                               const float* __restrict__ Ab,
                                               float* __restrict__ out) {
    int lane = threadIdx.x & 63, wave = threadIdx.x >> 6;
    int wm = wave >> 1, wn = wave & 1;
    int row0 = blockIdx.y * 256;
    int col0 = blockIdx.x * 128 + wn * 64;
    int rA = lane & 15, kA = (lane >> 4) * 8;
    v4f acc[4][4];
    for (int s = 0; s < 4; ++s)
        for (int f = 0; f < 4; ++f)
            acc[s][f] = (v4f){0.f, 0.f, 0.f, 0.f};

    for (int k0 = 0; k0 < R_OUT; k0 += 32) {
        v8h af[4];
#pragma unroll
        for (int s = 0; s < 4; ++s) {
            int r = row0 + (wm * 4 + s) * 16 + rA;
            af[s] = *reinterpret_cast<const v8h*>(Rbh + (size_t)r * R_OUT + k0 + kA);
        }
        v8h bf[4];
#pragma unroll
        for (int f = 0; f < 4; ++f) {
            int c = col0 + f * 16 + rA;
            bf[f] = *reinterpret_cast<const v8h*>(Awh + (size_t)c * R_OUT + k0 + kA);
        }
#pragma unroll
        for (int s = 0; s < 4; ++s)
#pragma unroll
            for (int f = 0; f < 4; ++f)
                acc[s][f] = __builtin_amdgcn_mfma_f32_16x16x32_f16(af[s], bf[f], acc[s][f], 0, 0, 0);
    }
#pragma unroll
    for (int f = 0; f < 4; ++f) {
        int col = col0 + f * 16 + (lane & 15);
        float bias = Ab[col];
#pragma unroll
        for (int s = 0; s < 4; ++s) {
#pragma unroll
            for (int r = 0; r < 4; ++r) {
                int row = row0 + (wm * 4 + s) * 16 + (lane >> 4) * 4 + r;
                out[(size_t)row * VOCAB + col] = acc[s][f][r] + bias;
            }
        }
    }
}

// ---------------- host launch ----------------

extern "C" void kernel_launch(void* const* d_in, const int* in_sizes, int n_in,
                              void* d_out, int out_size, void* d_ws, size_t ws_size,
                              hipStream_t stream) {
    const int*   x        = (const int*)d_in[0];
    const float* W_in     = (const float*)d_in[1];
    const int*   rec_rows = (const int*)d_in[2];
    const int*   rec_cols = (const int*)d_in[3];
    const float* rec_vals = (const float*)d_in[4];
    const float* a        = (const float*)d_in[5];
    const float* B_w      = (const float*)d_in[6];
    const float* A_w      = (const float*)d_in[7];
    const float* A_b      = (const float*)d_in[8];
    float* out = (float*)d_out;

    char* w = (char*)d_ws;
    size_t off = 0;
    auto alloc = [&](size_t bytes) { void* p = w + off; off = (off + bytes + 255) & ~(size_t)255; return p; };

    unsigned short* Hb     = (unsigned short*)alloc((size_t)2048 * N_RES * 2);   // 16.8 MB
    unsigned short* Rbh    = (unsigned short*)alloc((size_t)2048 * R_OUT * 2);   // 2.1 MB
    unsigned short* Bwh    = (unsigned short*)alloc((size_t)R_OUT * N_RES * 2);  // 4.2 MB
    unsigned short* Awh    = (unsigned short*)alloc((size_t)VOCAB * R_OUT * 2);  // 32.8 MB
    unsigned*       csr    = (unsigned*)alloc((size_t)NNZ_CAP * 4);              // 655 KB
    int*            rowptr = (int*)alloc(4097 * 4);
    int*            cnt    = (int*)alloc(4096 * 4);
    int*            cursor = (int*)alloc(4096 * 4);
    unsigned*       hx     = (unsigned*)alloc((size_t)2 * TEAMS * 4096 * 4);     // 256 KB
    unsigned*       flags  = (unsigned*)alloc(TEAMS * SLICES * 32 * 4);          // 16 KB

    hipMemsetAsync(csr, 0, (size_t)NNZ_CAP * 4, stream);
    hipMemsetAsync(cnt, 0, 4096 * 4, stream);
    hipMemsetAsync(flags, 0, TEAMS * SLICES * 32 * 4, stream);

    k_hist<<<(NNZ + 255) / 256, 256, 0, stream>>>(rec_rows, cnt);
    k_scan<<<1, 1024, 0, stream>>>(cnt, rowptr, cursor);
    k_fill<<<(NNZ + 255) / 256, 256, 0, stream>>>(rec_rows, rec_cols, rec_vals, cursor, csr);

    k_cvt<<<(R_OUT * N_RES / 8 + 255) / 256, 256, 0, stream>>>(B_w, Bwh, R_OUT * N_RES);
    k_cvt<<<(VOCAB * R_OUT / 8 + 255) / 256, 256, 0, stream>>>(A_w, Awh, VOCAB * R_OUT);

    k_steps<<<NWG, 256, 0, stream>>>(rowptr, csr, W_in, x, a, Hb, hx, flags);

    k_gemm1<<<dim3(R_OUT / 128, 2048 / 128), 512, 0, stream>>>(Hb, Bwh, Rbh);
    k_gemm2<<<dim3(VOCAB / 128, 2048 / 256), 512, 0, stream>>>(Rbh, Awh, A_b, out);
}

// Round 7
// 1839.599 us; speedup vs baseline: 1.0336x; 1.0336x over previous
//
#include <hip/hip_runtime.h>
#include <hip/hip_bf16.h>
#include <stdint.h>

#define N_RES 4096
#define BATCH 8
#define T_STEPS 256
#define VOCAB 32000
#define R_OUT 512
#define NNZ 131072
#define NNZ_CAP 163840
#define TEAMS 8             // one per batch
#define SLICES 8            // WGs per team
#define ROWS_PS 512         // rows per WG
#define NWG (TEAMS*SLICES)  // 64
#define CSR_CAP 18432       // entries per slice in LDS (padded mean ~17152, +10 sigma)

typedef _Float16 v8h __attribute__((ext_vector_type(8)));
typedef float v4f __attribute__((ext_vector_type(4)));

static __device__ __forceinline__ unsigned short f2h(float f) {
    _Float16 h = (_Float16)f;
    unsigned short u;
    __builtin_memcpy(&u, &h, 2);
    return u;
}
static __device__ __forceinline__ float h2f(unsigned short u) {
    _Float16 h;
    __builtin_memcpy(&h, &u, 2);
    return (float)h;
}

// ---------------- init / CSR build ----------------

__global__ __launch_bounds__(256) void k_hist(const int* __restrict__ rows,
                                              int* __restrict__ cnt) {
    int i = blockIdx.x * 256 + threadIdx.x;
    if (i < NNZ) atomicAdd(&cnt[rows[i]], 1);
}

// padded scan: each row's span rounded up to multiple of 4
__global__ __launch_bounds__(1024) void k_scan(const int* __restrict__ cnt,
                                               int* __restrict__ row_ptr,
                                               int* __restrict__ cursor) {
    __shared__ int sm[1024];
    int t = threadIdx.x;
    int base = t * 4;
    int c0 = (cnt[base] + 3) & ~3;
    int c1 = (cnt[base + 1] + 3) & ~3;
    int c2 = (cnt[base + 2] + 3) & ~3;
    int c3 = (cnt[base + 3] + 3) & ~3;
    int s = c0 + c1 + c2 + c3;
    sm[t] = s;
    __syncthreads();
    for (int off = 1; off < 1024; off <<= 1) {
        int v = (t >= off) ? sm[t - off] : 0;
        __syncthreads();
        sm[t] += v;
        __syncthreads();
    }
    int run = sm[t] - s;
    row_ptr[base] = run;     cursor[base] = run;     run += c0;
    row_ptr[base + 1] = run; cursor[base + 1] = run; run += c1;
    row_ptr[base + 2] = run; cursor[base + 2] = run; run += c2;
    row_ptr[base + 3] = run; cursor[base + 3] = run; run += c3;
    if (t == 1023) row_ptr[4096] = run;
}

// packed CSR entry: plane BYTE offset (col*4) in hi16, f16 value in lo16.
__global__ __launch_bounds__(256) void k_fill(const int* __restrict__ rows,
                                              const int* __restrict__ cols,
                                              const float* __restrict__ vals,
                                              int* __restrict__ cursor,
                                              unsigned* __restrict__ csr) {
    int i = blockIdx.x * 256 + threadIdx.x;
    if (i < NNZ) {
        int r = rows[i];
        unsigned off = (unsigned)(cols[i] << 2);
        int p = atomicAdd(&cursor[r], 1);
        csr[p] = (off << 16) | (unsigned)f2h(vals[i]);
    }
}

// ---------------- f32 -> f16 convert (for B_w, A_w) ----------------

__global__ __launch_bounds__(256) void k_cvt(const float* __restrict__ src,
                                             unsigned short* __restrict__ dst, int n) {
    int i = (blockIdx.x * 256 + threadIdx.x) * 8;
    if (i < n) {
        float4 a0 = *reinterpret_cast<const float4*>(src + i);
        float4 a1 = *reinterpret_cast<const float4*>(src + i + 4);
        unsigned short o[8] = { f2h(a0.x), f2h(a0.y), f2h(a0.z), f2h(a0.w),
                                f2h(a1.x), f2h(a1.y), f2h(a1.z), f2h(a1.w) };
        *reinterpret_cast<uint4*>(dst + i) = *reinterpret_cast<const uint4*>(o);
    }
}

// ---------------- persistent recurrence ----------------
// 64 WGs x 512 threads. team = wg&7 (batch), slice = wg>>3 (512 rows).
// Exchange: ONE self-validating tagged word per row. hx[par][team][row] :
// u32 = (epoch<<16)|f16(h). Publish = one relaxed agent store, fire-and-
// forget (no ack, no flag). Consume = one coalesced whole-plane pull (4 u64
// per thread, lane-contiguous), retrying only stale chunks; the tag IS the
// readiness signal, so the dependent chain is publish-visible -> pull.
// Overwrite safety (parity induction): a producer publishes epoch e only
// after completing its pull of e-1 (data dependency through compute), which
// required ALL rows of e-1; hence every consumer finished epoch e-2 (same
// parity buffer) before any e word lands. Stale tags across graph replays
// are harmless: a buffer's leftover tags (254/255 or 0xAAAA poison) can
// never equal the small epochs (1,2) expected when it is first reused, and
// from then on it always holds this-run e-2 or e. hx memset once per launch
// guards the very first (unpoisoned) call.

__global__ __launch_bounds__(512) void k_steps(const int* __restrict__ rowptr,
                                               const unsigned* __restrict__ csr,
                                               const float* __restrict__ W_in,
                                               const int* __restrict__ x,
                                               const float* __restrict__ a,
                                               unsigned short* __restrict__ Hb,
                                               unsigned* __restrict__ hx) {
    __shared__ float plane[4096];                       // 16 KB, identity layout
    __shared__ __align__(16) unsigned lcsr[CSR_CAP];    // 72 KB
    __shared__ int ltok[T_STEPS];                       // 1 KB

    int wg = blockIdx.x;
    int tid = threadIdx.x;
    int team = wg & 7;
    int slice = wg >> 3;
    int r_own = slice * ROWS_PS + tid;

    if (tid < T_STEPS) ltok[tid] = x[team * T_STEPS + tid];

    int j0 = rowptr[slice * ROWS_PS];
    int j1 = rowptr[slice * ROWS_PS + ROWS_PS];
    int cntE = j1 - j0;
    if (cntE > CSR_CAP) cntE = CSR_CAP;
    {
        const uint4* src = reinterpret_cast<const uint4*>(csr + j0);
        int n4 = cntE >> 2;
        for (int k = tid; k < n4; k += 512)
            reinterpret_cast<uint4*>(lcsr)[k] = src[k];
    }
    for (int k = tid; k < 4096; k += 512) plane[k] = 0.f;

    int js = rowptr[r_own] - j0;
    int je = rowptr[r_own + 1] - j0;
    if (js > CSR_CAP) js = CSR_CAP;
    if (je > CSR_CAP) je = CSR_CAP;
    float av = a[r_own];
    float oma = 1.f - av;
    int cb = tid * 4;                    // u64 chunk base: rows 8*tid..8*tid+7
    __syncthreads();

    float u_cur = W_in[(size_t)ltok[0] * N_RES + r_own];

    for (int t = 0; t < T_STEPS; ++t) {
        float acc = 0.f;
        for (int j = js; j < je; j += 4) {
            uint4 e4 = *reinterpret_cast<const uint4*>(lcsr + j);
            unsigned ee[4] = { e4.x, e4.y, e4.z, e4.w };
#pragma unroll
            for (int q = 0; q < 4; ++q) {
                float g = *reinterpret_cast<const float*>(
                    reinterpret_cast<const char*>(plane) + (ee[q] >> 16));
                acc += h2f((unsigned short)(ee[q] & 0xffffu)) * g;
            }
        }
        float hold = plane[r_own];
        float pre = u_cur + acc;
        pre = fminf(fmaxf(pre, -10.f), 10.f);
        float ex = __expf(2.f * pre);
        float th = 1.f - 2.f / (ex + 1.f);
        float hv = oma * hold + av * th;
        unsigned short hv16 = f2h(hv);

        if (t == T_STEPS - 1) {
            Hb[((size_t)(team * T_STEPS + t) << 12) + r_own] = hv16;
            break;
        }

        unsigned e = (unsigned)(t + 1);
        unsigned* xbase = hx + (((size_t)(e & 1u) * TEAMS + team) << 12);

        // publish own row: value+epoch in one word, fire-and-forget
        __hip_atomic_store(xbase + r_own, (e << 16) | (unsigned)hv16,
                           __ATOMIC_RELAXED, __HIP_MEMORY_SCOPE_AGENT);

        // off-critical-path work in the publish-latency shadow
        float u_nxt = W_in[(size_t)ltok[t + 1] * N_RES + r_own];
        Hb[((size_t)(team * T_STEPS + t) << 12) + r_own] = hv16;

        // pull whole team plane: 4 coalesced u64 chunks, retry only stale
        const unsigned long long* x64 =
            reinterpret_cast<const unsigned long long*>(xbase);
        unsigned long long g[4];
#pragma unroll
        for (int k = 0; k < 4; ++k)
            g[k] = __hip_atomic_load(x64 + cb + k,
                                     __ATOMIC_RELAXED, __HIP_MEMORY_SCOPE_AGENT);
        for (;;) {
            unsigned m = 0;
#pragma unroll
            for (int k = 0; k < 4; ++k) {
                unsigned t0 = (unsigned)(g[k] >> 16) & 0xffffu;
                unsigned t1 = (unsigned)(g[k] >> 48);
                m |= ((t0 != e) | (t1 != e)) ? (1u << k) : 0u;
            }
            if (!m) break;
#pragma unroll
            for (int k = 0; k < 4; ++k)
                if (m & (1u << k))
                    g[k] = __hip_atomic_load(x64 + cb + k,
                                             __ATOMIC_RELAXED, __HIP_MEMORY_SCOPE_AGENT);
        }
        __syncthreads();            // all gathers from old plane done
#pragma unroll
        for (int k = 0; k < 4; ++k) {
            float2 v;
            v.x = h2f((unsigned short)(g[k] & 0xffffu));
            v.y = h2f((unsigned short)((g[k] >> 32) & 0xffffu));
            *reinterpret_cast<float2*>(&plane[8 * tid + 2 * k]) = v;
        }
        u_cur = u_nxt;
        __syncthreads();            // new plane ready
    }
}

// ---------------- GEMM1: Rbh(2048x512,f16) = Hb(2048x4096,f16) @ Bwh^T ----------------

__global__ __launch_bounds__(512) void k_gemm1(const unsigned short* __restrict__ Hb,
                                               const unsigned short* __restrict__ Bwh,
                                               unsigned short* __restrict__ Rbh) {
    int lane = threadIdx.x & 63, wave = threadIdx.x >> 6;
    int wm = wave >> 1, wn = wave & 1;
    int row0 = blockIdx.y * 128;
    int col0 = blockIdx.x * 128 + wn * 64;
    int rA = lane & 15, kA = (lane >> 4) * 8;
    v4f acc[2][4];
    for (int s = 0; s < 2; ++s)
        for (int f = 0; f < 4; ++f)
            acc[s][f] = (v4f){0.f, 0.f, 0.f, 0.f};

    for (int k0 = 0; k0 < N_RES; k0 += 32) {
        v8h af[2];
#pragma unroll
        for (int s = 0; s < 2; ++s) {
            int r = row0 + (wm * 2 + s) * 16 + rA;
            af[s] = *reinterpret_cast<const v8h*>(Hb + (size_t)r * N_RES + k0 + kA);
        }
        v8h bf[4];
#pragma unroll
        for (int f = 0; f < 4; ++f) {
            int c = col0 + f * 16 + rA;
            bf[f] = *reinterpret_cast<const v8h*>(Bwh + (size_t)c * N_RES + k0 + kA);
        }
#pragma unroll
        for (int s = 0; s < 2; ++s)
#pragma unroll
            for (int f = 0; f < 4; ++f)
                acc[s][f] = __builtin_amdgcn_mfma_f32_16x16x32_f16(af[s], bf[f], acc[s][f], 0, 0, 0);
    }
#pragma unroll
    for (int s = 0; s < 2; ++s)
#pragma unroll
        for (int f = 0; f < 4; ++f) {
            int col = col0 + f * 16 + (lane & 15);
#pragma unroll
            for (int r = 0; r < 4; ++r) {
                int row = row0 + (wm * 2 + s) * 16 + (lane >> 4) * 4 + r;
                Rbh[(size_t)row * R_OUT + col] = f2h(acc[s][f][r]);
            }
        }
}

// ---------------- GEMM2: out(2048x32000,f32) = Rbh(f16) @ Awh^T + Ab ----------------

__global__ __launch_bounds__(512) void k_gemm2(const unsigned short* __restrict__ Rbh,
                                               const unsigned short* __restrict__ Awh,
                                               const float* __restrict__ Ab,
                                               float* __restrict__ out) {
    int lane = threadIdx.x & 63, wave = threadIdx.x >> 6;
    int wm = wave >> 1, wn = wave & 1;
    int row0 = blockIdx.y * 256;
    int col0 = blockIdx.x * 128 + wn * 64;
    int rA = lane & 15, kA = (lane >> 4) * 8;
    v4f acc[4][4];
    for (int s = 0; s < 4; ++s)
        for (int f = 0; f < 4; ++f)
            acc[s][f] = (v4f){0.f, 0.f, 0.f, 0.f};

    for (int k0 = 0; k0 < R_OUT; k0 += 32) {
        v8h af[4];
#pragma unroll
        for (int s = 0; s < 4; ++s) {
            int r = row0 + (wm * 4 + s) * 16 + rA;
            af[s] = *reinterpret_cast<const v8h*>(Rbh + (size_t)r * R_OUT + k0 + kA);
        }
        v8h bf[4];
#pragma unroll
        for (int f = 0; f < 4; ++f) {
            int c = col0 + f * 16 + rA;
            bf[f] = *reinterpret_cast<const v8h*>(Awh + (size_t)c * R_OUT + k0 + kA);
        }
#pragma unroll
        for (int s = 0; s < 4; ++s)
#pragma unroll
            for (int f = 0; f < 4; ++f)
                acc[s][f] = __builtin_amdgcn_mfma_f32_16x16x32_f16(af[s], bf[f], acc[s][f], 0, 0, 0);
    }
#pragma unroll
    for (int f = 0; f < 4; ++f) {
        int col = col0 + f * 16 + (lane & 15);
        float bias = Ab[col];
#pragma unroll
        for (int s = 0; s < 4; ++s) {
#pragma unroll
            for (int r = 0; r < 4; ++r) {
                int row = row0 + (wm * 4 + s) * 16 + (lane >> 4) * 4 + r;
                out[(size_t)row * VOCAB + col] = acc[s][f][r] + bias;
            }
        }
    }
}

// ---------------- host launch ----------------

extern "C" void kernel_launch(void* const* d_in, const int* in_sizes, int n_in,
                              void* d_out, int out_size, void* d_ws, size_t ws_size,
                              hipStream_t stream) {
    const int*   x        = (const int*)d_in[0];
    const float* W_in     = (const float*)d_in[1];
    const int*   rec_rows = (const int*)d_in[2];
    const int*   rec_cols = (const int*)d_in[3];
    const float* rec_vals = (const float*)d_in[4];
    const float* a        = (const float*)d_in[5];
    const float* B_w      = (const float*)d_in[6];
    const float* A_w      = (const float*)d_in[7];
    const float* A_b      = (const float*)d_in[8];
    float* out = (float*)d_out;

    char* w = (char*)d_ws;
    size_t off = 0;
    auto alloc = [&](size_t bytes) { void* p = w + off; off = (off + bytes + 255) & ~(size_t)255; return p; };

    unsigned short* Hb     = (unsigned short*)alloc((size_t)2048 * N_RES * 2);   // 16.8 MB
    unsigned short* Rbh    = (unsigned short*)alloc((size_t)2048 * R_OUT * 2);   // 2.1 MB
    unsigned short* Bwh    = (unsigned short*)alloc((size_t)R_OUT * N_RES * 2);  // 4.2 MB
    unsigned short* Awh    = (unsigned short*)alloc((size_t)VOCAB * R_OUT * 2);  // 32.8 MB
    unsigned*       csr    = (unsigned*)alloc((size_t)NNZ_CAP * 4);              // 655 KB
    int*            rowptr = (int*)alloc(4097 * 4);
    int*            cnt    = (int*)alloc(4096 * 4);
    int*            cursor = (int*)alloc(4096 * 4);
    unsigned*       hx     = (unsigned*)alloc((size_t)2 * TEAMS * 4096 * 4);     // 256 KB

    hipMemsetAsync(csr, 0, (size_t)NNZ_CAP * 4, stream);
    hipMemsetAsync(cnt, 0, 4096 * 4, stream);
    hipMemsetAsync(hx, 0, (size_t)2 * TEAMS * 4096 * 4, stream);

    k_hist<<<(NNZ + 255) / 256, 256, 0, stream>>>(rec_rows, cnt);
    k_scan<<<1, 1024, 0, stream>>>(cnt, rowptr, cursor);
    k_fill<<<(NNZ + 255) / 256, 256, 0, stream>>>(rec_rows, rec_cols, rec_vals, cursor, csr);

    k_cvt<<<(R_OUT * N_RES / 8 + 255) / 256, 256, 0, stream>>>(B_w, Bwh, R_OUT * N_RES);
    k_cvt<<<(VOCAB * R_OUT / 8 + 255) / 256, 256, 0, stream>>>(A_w, Awh, VOCAB * R_OUT);

    k_steps<<<NWG, 512, 0, stream>>>(rowptr, csr, W_in, x, a, Hb, hx);

    k_gemm1<<<dim3(R_OUT / 128, 2048 / 128), 512, 0, stream>>>(Hb, Bwh, Rbh);
    k_gemm2<<<dim3(VOCAB / 128, 2048 / 256), 512, 0, stream>>>(Rbh, Awh, A_b, out);
}